// Round 2
// baseline (25.159 us; speedup 1.0000x reference)
//
#include <hip/hip_runtime.h>

// LocalLinearLayer: out[b,o,c] = bias[o] + sum_{j=0..24} W[o, o+j] * xp[b, o+j, c]
// x: [32, 4096, 64] f32, W: [4096, 4120] f32 (only the 25-wide band used), b: [4096]
// xp padding: taps p<12 copy x[p], p>=4108 copy x[p-24], else x[p-12].

constexpr int Lseq = 4096;
constexpr int WIN  = 25;
constexpr int PAD  = 12;           // (WIN-1)/2
constexpr int C4   = 16;           // 64 channels as 16 float4 groups
constexpr int KO   = 8;            // outputs per thread (register sliding window)
constexpr int OG   = 16;           // o-groups per block
constexpr int O_TILE = KO * OG;    // 128 outputs per block
constexpr int ROWS = KO + WIN - 1; // 32 x-rows per thread
constexpr int WSTRIDE = 25;        // LDS floats per W row; odd -> 4 o-groups/wave on distinct banks

// W is [4096, 4120] row-major; band element (o, j) lives at o*4120 + (o+j) = o*4121 + j.

template <bool EDGE>
__device__ __forceinline__ void compute_tile(
    const float4* __restrict__ x4b,   // x as float4, offset to (batch, channel-group)
    const float*  __restrict__ wl,    // LDS weights for this o-group: wl[k*24 + r] = W[o0+k, j=r-k]
    const float*  __restrict__ bias,
    float4*       __restrict__ out4b,
    int o0)
{
    float4 acc[KO];
#pragma unroll
    for (int k = 0; k < KO; ++k) {
        float bv = bias[o0 + k];
        acc[k] = make_float4(bv, bv, bv, bv);
    }

#pragma unroll
    for (int r = 0; r < ROWS; ++r) {
        const int p = o0 + r;             // padded-coordinate tap index
        int t;
        if (EDGE) {
            t = (p < PAD) ? p : ((p < Lseq + PAD) ? (p - PAD) : (p - 2 * PAD));
        } else {
            t = p - PAD;
        }
        const float4 xv = x4b[(size_t)t * C4];
#pragma unroll
        for (int k = 0; k < KO; ++k) {
            const int j = r - k;          // compile-time after unroll
            if (j >= 0 && j < WIN) {
                // LDS read with compile-time immediate offset: addr = (og*8+k)*25 + j
                const float w = wl[k * (WSTRIDE - 1) + r];
                acc[k].x = fmaf(w, xv.x, acc[k].x);
                acc[k].y = fmaf(w, xv.y, acc[k].y);
                acc[k].z = fmaf(w, xv.z, acc[k].z);
                acc[k].w = fmaf(w, xv.w, acc[k].w);
            }
        }
    }

#pragma unroll
    for (int k = 0; k < KO; ++k)
        out4b[(size_t)(o0 + k) * C4] = acc[k];
}

__global__ __launch_bounds__(256) void lll_kernel(
    const float* __restrict__ x, const float* __restrict__ W,
    const float* __restrict__ bias, float* __restrict__ out)
{
    __shared__ float w_lds[O_TILE * WSTRIDE];   // 12.8 KB

    const int tid = threadIdx.x;
    const int tiles_per_batch = Lseq / O_TILE;      // 32
    const int b     = blockIdx.x / tiles_per_batch;
    const int tile  = blockIdx.x % tiles_per_batch;
    const int o_blk = tile * O_TILE;

    // ---- Stage the W band into LDS: 2 threads per output row ----
    {
        const int row = tid >> 1;
        const int h   = tid & 1;
        const float* wr = W + (size_t)(o_blk + row) * 4121;
        float* dst = w_lds + row * WSTRIDE;
        if (h == 0) {
#pragma unroll
            for (int c = 0; c < 13; ++c) dst[c] = wr[c];
        } else {
#pragma unroll
            for (int c = 13; c < WIN; ++c) dst[c] = wr[c];
        }
    }
    __syncthreads();

    const int c4 = tid & 15;
    const int og = tid >> 4;
    const int o0 = o_blk + og * KO;

    const float4* x4b   = (const float4*)x + (size_t)b * Lseq * C4 + c4;
    float4*       out4b = (float4*)out     + (size_t)b * Lseq * C4 + c4;
    const float*  wl    = w_lds + og * KO * WSTRIDE;

    const bool interior = (o0 >= PAD) && (o0 + ROWS <= Lseq + PAD);
    if (interior)
        compute_tile<false>(x4b, wl, bias, out4b, o0);
    else
        compute_tile<true>(x4b, wl, bias, out4b, o0);
}

extern "C" void kernel_launch(void* const* d_in, const int* in_sizes, int n_in,
                              void* d_out, int out_size, void* d_ws, size_t ws_size,
                              hipStream_t stream) {
    const float* x    = (const float*)d_in[0];
    const float* W    = (const float*)d_in[1];
    const float* bias = (const float*)d_in[2];
    float*       out  = (float*)d_out;

    const int B = 32;
    const dim3 grid(B * (Lseq / O_TILE));   // 1024 blocks, 4 per CU
    lll_kernel<<<grid, 256, 0, stream>>>(x, W, bias, out);
}

// Round 3
// 23.782 us; speedup vs baseline: 1.0579x; 1.0579x over previous
//
#include <hip/hip_runtime.h>

// LocalLinearLayer via banded bf16 MFMA.
// out[b,o,c] = bias[o] + sum_{j=0..24} W[o, o+j] * xp[b, o+j, c]
// xp[q] = x[q] (q<12), x[q-12] (12<=q<4108), x[q-24] (q>=4108)
//
// MFMA decomposition (16x16x32 bf16): for a 16-output tile at o0,
//   out[o0+m][c] = sum_kappa A[m][kappa] * B[kappa][c],  kappa in [0,64)
//   A[m][kappa] = W[o0+m, j=kappa-m] (0<=j<25, else 0),  B[kappa][c] = xp[o0+kappa][c]
// A is pre-baked into d_ws as AkG[o][p] = W[o, p-(o&63)] zero-padded, p in [0,120),
// so wave w of a 64-output block reads A at p = 16w + kappa (aligned dwordx4).

typedef __attribute__((ext_vector_type(8))) short short8;
typedef __attribute__((ext_vector_type(4))) float f32x4;

constexpr int Lseq = 4096;
constexpr int C    = 64;
constexpr int WIN  = 25;
constexpr int PAD  = 12;
constexpr int O_B  = 64;            // outputs per block (4 waves x 16)
constexpr int PWIN = O_B + 48;      // 112 taps staged per block
constexpr int PL   = 120;           // row length (bf16) for AkG and x_lds; 240 B, 16B-aligned
constexpr int NB   = 32;            // batch
constexpr size_t WS_NEEDED = (size_t)Lseq * PL * sizeof(ushort);  // 983040

__device__ __forceinline__ ushort f2bf(float f) {
    union { float f; uint u; } v; v.f = f;
    uint r = v.u + 0x7FFFu + ((v.u >> 16) & 1u);   // round-to-nearest-even
    return (ushort)(r >> 16);
}

__device__ __forceinline__ int tap_to_t(int q) {
    int t = (q < PAD) ? q : ((q < Lseq + PAD) ? q - PAD : q - 2 * PAD);
    return t > Lseq - 1 ? Lseq - 1 : t;   // clamp (clamped taps always hit zero weights)
}

// ---- pre-kernel: bake zero-padded pre-shifted bf16 weight band into ws ----
__global__ __launch_bounds__(256) void bake_w(const float* __restrict__ W,
                                              ushort* __restrict__ akg) {
    int gid = blockIdx.x * 256 + threadIdx.x;      // 4096 * 64
    int o = gid >> 6, sl = gid & 63;
    if (sl >= PL / 2) return;
    int p0 = sl * 2;
    int sh = o & (O_B - 1);
    uint pk = 0;
#pragma unroll
    for (int i = 0; i < 2; ++i) {
        int j = p0 + i - sh;
        float v = (j >= 0 && j < WIN) ? W[(size_t)o * 4121 + j] : 0.f;  // W[o][o+j]
        pk |= (uint)f2bf(v) << (16 * i);
    }
    *(uint*)(akg + (size_t)o * PL + p0) = pk;
}

// ---- main kernel ----
__global__ __launch_bounds__(256) void lll_mfma(const float* __restrict__ x,
                                                const ushort* __restrict__ akg,
                                                const float* __restrict__ bias,
                                                float* __restrict__ out) {
    __shared__ ushort x_lds[C * PL];               // 15360 B

    const int bid   = blockIdx.x;
    const int tile  = bid >> 5;                    // 0..63  (consecutive bids share AkG tile)
    const int b     = bid & 31;
    const int blk_o = tile * O_B;

    const float4* xb = (const float4*)(x + (size_t)b * Lseq * C);

    // stage x -> x_lds[c][p] bf16 (transposed), p in [0,112)
    for (int s = 0; s < 4; ++s) {
        int u = threadIdx.x + 256 * s;
        if (u < 16 * (PWIN / 2)) {                 // 896 units: (c4, tap-pair)
            int c4 = u & 15, up = u >> 4;
            int p0 = up * 2;
            int t0 = tap_to_t(blk_o + p0);
            int t1 = tap_to_t(blk_o + p0 + 1);
            float4 f0 = xb[(size_t)t0 * 16 + c4];
            float4 f1 = xb[(size_t)t1 * 16 + c4];
            const float a0[4] = {f0.x, f0.y, f0.z, f0.w};
            const float a1[4] = {f1.x, f1.y, f1.z, f1.w};
#pragma unroll
            for (int i = 0; i < 4; ++i) {
                uint pk = (uint)f2bf(a0[i]) | ((uint)f2bf(a1[i]) << 16);
                *(uint*)&x_lds[(c4 * 4 + i) * PL + p0] = pk;
            }
        }
    }
    __syncthreads();

    const int lane = threadIdx.x & 63;
    const int w    = threadIdx.x >> 6;             // wave in block -> 16-output subtile
    const int m    = lane & 15;
    const int quad = lane >> 4;
    const int o0   = blk_o + w * 16;

    // acc init = bias broadcast (C-in of MFMA). D row = quad*4+reg, col = m+16g.
    f32x4 acc[4];
#pragma unroll
    for (int r = 0; r < 4; ++r) {
        float bv = bias[o0 + quad * 4 + r];
#pragma unroll
        for (int g = 0; g < 4; ++g) acc[g][r] = bv;
    }

    // A-frag: lane holds A[m][kappa], kappa = ch*32 + quad*8 + e  -> AkG[o0+m][16w + kappa]
    const ushort* arow = akg + (size_t)(o0 + m) * PL + w * 16 + quad * 8;
#pragma unroll
    for (int ch = 0; ch < 2; ++ch) {
        short8 a = *(const short8*)(arow + ch * 32);
        const int poff = w * 16 + ch * 32 + quad * 8;
#pragma unroll
        for (int g = 0; g < 4; ++g) {
            // B-frag: lane holds B[kappa][n= m+16g] = x_lds[m+16g][16w + kappa]
            short8 bf = *(const short8*)&x_lds[(m + 16 * g) * PL + poff];
            acc[g] = __builtin_amdgcn_mfma_f32_16x16x32_bf16(a, bf, acc[g], 0, 0, 0);
        }
    }

    float* ob = out + (size_t)b * Lseq * C;
#pragma unroll
    for (int g = 0; g < 4; ++g)
#pragma unroll
        for (int r = 0; r < 4; ++r)
            ob[(size_t)(o0 + quad * 4 + r) * C + m + 16 * g] = acc[g][r];
}

// ---- fallback (R1 kernel, f32 scalar path) in case ws_size is too small ----
constexpr int KO = 8, OG = 16, O_TILE = KO * OG, ROWS = KO + WIN - 1;

template <bool EDGE>
__device__ __forceinline__ void compute_tile_f32(
    const float4* __restrict__ x4b, const float* __restrict__ W,
    const float* __restrict__ bias, float4* __restrict__ out4b, int o0)
{
    float4 acc[KO];
#pragma unroll
    for (int k = 0; k < KO; ++k) { float bv = bias[o0 + k]; acc[k] = make_float4(bv, bv, bv, bv); }
    int wbase[KO];
#pragma unroll
    for (int k = 0; k < KO; ++k) wbase[k] = (o0 + k) * 4121 - k;
#pragma unroll
    for (int r = 0; r < ROWS; ++r) {
        const int p = o0 + r;
        int t = EDGE ? ((p < PAD) ? p : ((p < Lseq + PAD) ? p - PAD : p - 2 * PAD)) : (p - PAD);
        const float4 xv = x4b[(size_t)t * 16];
#pragma unroll
        for (int k = 0; k < KO; ++k) {
            const int j = r - k;
            if (j >= 0 && j < WIN) {
                const float w = W[(size_t)(wbase[k] + r)];
                acc[k].x = fmaf(w, xv.x, acc[k].x); acc[k].y = fmaf(w, xv.y, acc[k].y);
                acc[k].z = fmaf(w, xv.z, acc[k].z); acc[k].w = fmaf(w, xv.w, acc[k].w);
            }
        }
    }
#pragma unroll
    for (int k = 0; k < KO; ++k) out4b[(size_t)(o0 + k) * 16] = acc[k];
}

__global__ __launch_bounds__(256) void lll_f32(
    const float* __restrict__ x, const float* __restrict__ W,
    const float* __restrict__ bias, float* __restrict__ out)
{
    const int tid = threadIdx.x;
    const int tiles = Lseq / O_TILE;
    const int b = blockIdx.x / tiles, tile = blockIdx.x % tiles;
    const int o0 = tile * O_TILE + (tid >> 4) * KO;
    const int c4 = tid & 15;
    const float4* x4b = (const float4*)x + (size_t)b * Lseq * 16 + c4;
    float4* out4b = (float4*)out + (size_t)b * Lseq * 16 + c4;
    const bool interior = (o0 >= PAD) && (o0 + ROWS <= Lseq + PAD);
    if (interior) compute_tile_f32<false>(x4b, W, bias, out4b, o0);
    else          compute_tile_f32<true>(x4b, W, bias, out4b, o0);
}

extern "C" void kernel_launch(void* const* d_in, const int* in_sizes, int n_in,
                              void* d_out, int out_size, void* d_ws, size_t ws_size,
                              hipStream_t stream) {
    const float* x    = (const float*)d_in[0];
    const float* W    = (const float*)d_in[1];
    const float* bias = (const float*)d_in[2];
    float*       out  = (float*)d_out;

    if (ws_size >= WS_NEEDED) {
        ushort* akg = (ushort*)d_ws;
        bake_w<<<1024, 256, 0, stream>>>(W, akg);
        lll_mfma<<<NB * (Lseq / O_B), 256, 0, stream>>>(x, akg, bias, out);  // 2048 blocks
    } else {
        lll_f32<<<NB * (Lseq / O_TILE), 256, 0, stream>>>(x, W, bias, out);
    }
}

// Round 4
// 23.596 us; speedup vs baseline: 1.0662x; 1.0079x over previous
//
#include <hip/hip_runtime.h>

// LocalLinearLayer via banded bf16 MFMA, O_B=128.
// out[b,o,c] = bias[o] + sum_{j=0..24} W[o, o+j] * xp[b, o+j, c]
// xp[q] = x[q] (q<12), x[q-12] (12<=q<4108), x[q-24] (q>=4108)
//
// MFMA 16x16x32 decomposition per 16-output tile at o0:
//   out[o0+m][c] = sum_{kappa<64} A[m][kappa] * B[kappa][c]
//   A[m][kappa] = W[o0+m, j=kappa-m] (0<=j<25 else 0),  B[kappa][c] = xp[o0+kappa][c]
// A pre-baked in d_ws: akg[o][p] = W[o, p-(o&63)] zero-padded, p in [0,120).
// A 128-output block spans two 64-groups; tile t16 (0..7) reads A at
// column offset (t16&3)*16 (max 111 < 120).

typedef __attribute__((ext_vector_type(8))) short short8;
typedef __attribute__((ext_vector_type(4))) float f32x4;

constexpr int Lseq = 4096;
constexpr int C    = 64;
constexpr int WIN  = 25;
constexpr int PAD  = 12;
constexpr int O_B  = 128;           // outputs per block (4 waves x 2 tiles x 16)
constexpr int PWIN = O_B + 48;      // 176 taps staged per block
constexpr int PLX  = 184;           // x_lds row stride (shorts): 368B, 16B-aligned, 2-way-free banks
constexpr int PL   = 120;           // akg row length (shorts)
constexpr int NB   = 32;
constexpr size_t WS_NEEDED = (size_t)Lseq * PL * sizeof(ushort);  // 983040

__device__ __forceinline__ ushort f2bf(float f) {
    union { float f; uint u; } v; v.f = f;
    uint r = v.u + 0x7FFFu + ((v.u >> 16) & 1u);
    return (ushort)(r >> 16);
}

__device__ __forceinline__ int tap_to_t(int q) {
    int t = (q < PAD) ? q : ((q < Lseq + PAD) ? q - PAD : q - 2 * PAD);
    return t > Lseq - 1 ? Lseq - 1 : t;   // clamped taps always meet zero weights
}

// ---- bake zero-padded pre-shifted bf16 weight band into ws (unchanged from R3) ----
__global__ __launch_bounds__(256) void bake_w(const float* __restrict__ W,
                                              ushort* __restrict__ akg) {
    int gid = blockIdx.x * 256 + threadIdx.x;
    int o = gid >> 6, sl = gid & 63;
    if (sl >= PL / 2) return;
    int p0 = sl * 2;
    int sh = o & 63;
    uint pk = 0;
#pragma unroll
    for (int i = 0; i < 2; ++i) {
        int j = p0 + i - sh;
        float v = (j >= 0 && j < WIN) ? W[(size_t)o * 4121 + j] : 0.f;
        pk |= (uint)f2bf(v) << (16 * i);
    }
    *(uint*)(akg + (size_t)o * PL + p0) = pk;
}

// ---- main kernel: 256 threads, 128 outputs/block ----
__global__ __launch_bounds__(256) void lll_mfma(const float* __restrict__ x,
                                                const ushort* __restrict__ akg,
                                                const float* __restrict__ bias,
                                                float* __restrict__ out) {
    __shared__ ushort x_lds[C * PLX];              // 23.0 KB

    const int bid   = blockIdx.x;
    const int tile  = bid >> 5;                    // consecutive bids: same tile, diff batch
    const int b     = bid & 31;                    //  -> bid & bid+32 share XCD slot (halo L2 reuse)
    const int blk_o = tile * O_B;

    const float4* xb = (const float4*)(x + (size_t)b * Lseq * C);

    // stage x -> x_lds[c][p] bf16 transposed, p in [0,176)
#pragma unroll
    for (int s = 0; s < 6; ++s) {
        int u = threadIdx.x + 256 * s;
        if (u < 16 * (PWIN / 2)) {                 // 1408 units: (c4, tap-pair)
            int c4 = u & 15, tp = u >> 4;
            int p0 = tp * 2;
            int t0 = tap_to_t(blk_o + p0);
            int t1 = tap_to_t(blk_o + p0 + 1);
            float4 f0 = xb[(size_t)t0 * 16 + c4];
            float4 f1 = xb[(size_t)t1 * 16 + c4];
            const float a0[4] = {f0.x, f0.y, f0.z, f0.w};
            const float a1[4] = {f1.x, f1.y, f1.z, f1.w};
#pragma unroll
            for (int i = 0; i < 4; ++i) {
                uint pk = (uint)f2bf(a0[i]) | ((uint)f2bf(a1[i]) << 16);
                *(uint*)&x_lds[(c4 * 4 + i) * PLX + p0] = pk;
            }
        }
    }
    __syncthreads();

    const int lane = threadIdx.x & 63;
    const int w    = threadIdx.x >> 6;
    const int m    = lane & 15;
    const int quad = lane >> 4;

    float* ob = out + (size_t)b * Lseq * C;

#pragma unroll
    for (int i = 0; i < 2; ++i) {                  // 2 tiles per wave
        const int t16 = w * 2 + i;
        const int o0  = blk_o + t16 * 16;

        f32x4 acc[4];
#pragma unroll
        for (int r = 0; r < 4; ++r) {
            float bv = bias[o0 + quad * 4 + r];
#pragma unroll
            for (int g = 0; g < 4; ++g) acc[g][r] = bv;
        }

        const ushort* arow = akg + (size_t)(o0 + m) * PL + (t16 & 3) * 16 + quad * 8;
#pragma unroll
        for (int ch = 0; ch < 2; ++ch) {
            short8 a = *(const short8*)(arow + ch * 32);
            const int poff = t16 * 16 + ch * 32 + quad * 8;
#pragma unroll
            for (int g = 0; g < 4; ++g) {
                short8 bf = *(const short8*)&x_lds[(m + 16 * g) * PLX + poff];
                acc[g] = __builtin_amdgcn_mfma_f32_16x16x32_bf16(a, bf, acc[g], 0, 0, 0);
            }
        }

#pragma unroll
        for (int g = 0; g < 4; ++g)
#pragma unroll
            for (int r = 0; r < 4; ++r)
                ob[(size_t)(o0 + quad * 4 + r) * C + m + 16 * g] = acc[g][r];
    }
}

// ---- fallback f32 path (ws too small) ----
constexpr int KO = 8, OG = 16, O_TILE = KO * OG, ROWS = KO + WIN - 1;

template <bool EDGE>
__device__ __forceinline__ void compute_tile_f32(
    const float4* __restrict__ x4b, const float* __restrict__ W,
    const float* __restrict__ bias, float4* __restrict__ out4b, int o0)
{
    float4 acc[KO];
#pragma unroll
    for (int k = 0; k < KO; ++k) { float bv = bias[o0 + k]; acc[k] = make_float4(bv, bv, bv, bv); }
    int wbase[KO];
#pragma unroll
    for (int k = 0; k < KO; ++k) wbase[k] = (o0 + k) * 4121 - k;
#pragma unroll
    for (int r = 0; r < ROWS; ++r) {
        const int p = o0 + r;
        int t = EDGE ? ((p < PAD) ? p : ((p < Lseq + PAD) ? p - PAD : p - 2 * PAD)) : (p - PAD);
        const float4 xv = x4b[(size_t)t * 16];
#pragma unroll
        for (int k = 0; k < KO; ++k) {
            const int j = r - k;
            if (j >= 0 && j < WIN) {
                const float w = W[(size_t)(wbase[k] + r)];
                acc[k].x = fmaf(w, xv.x, acc[k].x); acc[k].y = fmaf(w, xv.y, acc[k].y);
                acc[k].z = fmaf(w, xv.z, acc[k].z); acc[k].w = fmaf(w, xv.w, acc[k].w);
            }
        }
    }
#pragma unroll
    for (int k = 0; k < KO; ++k) out4b[(size_t)(o0 + k) * 16] = acc[k];
}

__global__ __launch_bounds__(256) void lll_f32(
    const float* __restrict__ x, const float* __restrict__ W,
    const float* __restrict__ bias, float* __restrict__ out)
{
    const int tid = threadIdx.x;
    const int tiles = Lseq / O_TILE;
    const int b = blockIdx.x / tiles, tile = blockIdx.x % tiles;
    const int o0 = tile * O_TILE + (tid >> 4) * KO;
    const int c4 = tid & 15;
    const float4* x4b = (const float4*)x + (size_t)b * Lseq * 16 + c4;
    float4* out4b = (float4*)out + (size_t)b * Lseq * 16 + c4;
    const bool interior = (o0 >= PAD) && (o0 + ROWS <= Lseq + PAD);
    if (interior) compute_tile_f32<false>(x4b, W, bias, out4b, o0);
    else          compute_tile_f32<true>(x4b, W, bias, out4b, o0);
}

extern "C" void kernel_launch(void* const* d_in, const int* in_sizes, int n_in,
                              void* d_out, int out_size, void* d_ws, size_t ws_size,
                              hipStream_t stream) {
    const float* x    = (const float*)d_in[0];
    const float* W    = (const float*)d_in[1];
    const float* bias = (const float*)d_in[2];
    float*       out  = (float*)d_out;

    if (ws_size >= WS_NEEDED) {
        ushort* akg = (ushort*)d_ws;
        bake_w<<<1024, 256, 0, stream>>>(W, akg);
        lll_mfma<<<NB * (Lseq / O_B), 256, 0, stream>>>(x, akg, bias, out);  // 1024 blocks
    } else {
        lll_f32<<<NB * (Lseq / O_TILE), 256, 0, stream>>>(x, W, bias, out);
    }
}